// Round 5
// baseline (452.705 us; speedup 1.0000x reference)
//
#include <hip/hip_runtime.h>

#define MM 64
#define NN 16
#define DDIM 300
#define FNUM 768
#define SURF_LL 4
#define CTX_LL 50
#define DOC_LL 100
#define BODY_LL 200
#define NHEADS 5
#define HDIM 60

// GEMM dims for conv_mc:  C[GM][GN] = A[GM][GK] * B^T, K padded 1500->1536
#define GM 2944   // 64 m * 46 t
#define GK 1536
#define GN 768

typedef unsigned short u16;
typedef unsigned int u32;
typedef __attribute__((ext_vector_type(8))) short short8;
typedef __attribute__((ext_vector_type(4))) float f32x4;

// ---- workspace layout (float offsets) ----
#define OFF_MSG    0                    // mention emb [256][300]
#define OFF_CTX2G  76800                // contexts_ids emb [3200][300]
#define OFF_CANDG  1036800              // men2cands emb [1024][300]
#define OFF_MS     1344000              // ms [64][768]
#define OFF_MC     1393152              // mc [64][768] (atomic mean accum)
#define OFF_PV0    1442304              // [16][5][4][60] per-qt partial max
#define OFF_PV1    1461504              // [16][5][7][60] per-qt partial max
#define OFF_ASC    1495104              // att logit [16] (atomic accum)
#define OFF_LATT   1495120              // [64][16]
#define OFF_ABF    1496144              // u16[GM*GK]
#define OFF_WTMC   (OFF_ABF + GM*GK/2)  // u16[GN*GK]
#define OFF_WTMS   (OFF_WTMC + GN*GK/2) // float[600*768]

__device__ __forceinline__ u16 f2bf(float x) {
  union { float f; u32 u; } v; v.f = x;
  u32 r = v.u + 0x7FFFu + ((v.u >> 16) & 1u);
  return (u16)(r >> 16);
}

// ---------------------------------------------------------------------------
// MEGA-PREP: gather embeddings + zero mc + zero att logit + im2col bf16 +
// weight repacks.
// blocks: [0,5250) gather ; [5250,5442) mc zero ; 5442 logit zero ;
//         [5443,14275) abuild ; [14275,16579) wtmc ; [16579,18379) wtms
__global__ __launch_bounds__(256) void mega_prep_kernel(
    const float* __restrict__ embed,
    const int* __restrict__ mention_vec,
    const int* __restrict__ context_vec,
    const int* __restrict__ contexts_ids,
    const int* __restrict__ men2cands,
    const float* __restrict__ Wmc,
    const float* __restrict__ Wms,
    float* __restrict__ dst, float* __restrict__ mc,
    float* __restrict__ att_logit,
    u32* __restrict__ Abf, u32* __restrict__ WTmc, float* __restrict__ WTms) {
  int bid = blockIdx.x;
  if (bid < 5250) {
    int e = bid * 256 + threadIdx.x;
    int row = e / DDIM;
    int col = e - row * DDIM;
    int tok;
    if (row < 256)       tok = mention_vec[row];
    else if (row < 3456) tok = contexts_ids[row - 256];
    else                 tok = men2cands[row - 3456];
    dst[e] = embed[(size_t)tok * DDIM + col];
  } else if (bid < 5442) {
    mc[(bid - 5250) * 256 + threadIdx.x] = 0.f;
  } else if (bid == 5442) {
    if (threadIdx.x < NN) att_logit[threadIdx.x] = 0.f;
  } else if (bid < 14275) {
    int idx = (bid - 5443) * 256 + threadIdx.x;  // one u32 = 2 bf16
    int r = idx / (GK / 2);
    int kp = idx - r * (GK / 2);
    int k = kp * 2;
    int m = r / 46, t = r - m * 46;
    u32 out = 0;
#pragma unroll
    for (int j = 0; j < 2; j++) {
      int kj = k + j;
      u16 h = 0;
      if (kj < 1500) {
        int tap = kj / 300;
        int d = kj - tap * 300;
        int tok = context_vec[m * CTX_LL + t + tap];
        h = f2bf(embed[(size_t)tok * DDIM + d]);
      }
      out |= (u32)h << (16 * j);
    }
    Abf[idx] = out;
  } else if (bid < 16579) {
    int idx = (bid - 14275) * 256 + threadIdx.x;
    int n = idx / (GK / 2);
    int kp = idx - n * (GK / 2);
    int k = kp * 2;
    u32 out = 0;
#pragma unroll
    for (int j = 0; j < 2; j++) {
      int kj = k + j;
      u16 h = 0;
      if (kj < 1500) {
        int tap = kj / 300;
        int d = kj - tap * 300;
        h = f2bf(Wmc[(size_t)n * 1500 + d * 5 + tap]);
      }
      out |= (u32)h << (16 * j);
    }
    WTmc[idx] = out;
  } else {
    int idx = (bid - 16579) * 256 + threadIdx.x;  // 600*768
    int k = idx / FNUM;
    int f = idx - k * FNUM;
    WTms[idx] = Wms[(size_t)f * 600 + k];
  }
}

// ---------------------------------------------------------------------------
// bf16 MFMA GEMM with fused relu+mean epilogue (atomicAdd into mc).
__global__ __launch_bounds__(256) void conv_gemm_kernel(
    const u16* __restrict__ A,    // [GM][GK] bf16
    const u16* __restrict__ B,    // [GN][GK] bf16 (n-major)
    const float* __restrict__ bias,
    float* __restrict__ mc) {     // [64][768]
  int bn = blockIdx.x, bm = blockIdx.y;
  __shared__ u16 As[64][72];
  __shared__ u16 Bs[64][72];
  int tid = threadIdx.x;
  int w = tid >> 6, lane = tid & 63;
  int wr = w >> 1, wc = w & 1;
  int lg = lane >> 4, lm = lane & 15;
  f32x4 acc[2][2];
#pragma unroll
  for (int i = 0; i < 2; i++)
#pragma unroll
    for (int j = 0; j < 2; j++) acc[i][j] = (f32x4)0.f;
  int c0row = tid >> 3, ck = (tid & 7) * 8;
  const u16* Ag = A + (size_t)(bm * 64) * GK;
  const u16* Bg = B + (size_t)(bn * 64) * GK;
  for (int kt = 0; kt < GK / 64; kt++) {
    int k0 = kt * 64;
    uint4 av0 = *(const uint4*)(Ag + (size_t)c0row * GK + k0 + ck);
    uint4 av1 = *(const uint4*)(Ag + (size_t)(c0row + 32) * GK + k0 + ck);
    uint4 bv0 = *(const uint4*)(Bg + (size_t)c0row * GK + k0 + ck);
    uint4 bv1 = *(const uint4*)(Bg + (size_t)(c0row + 32) * GK + k0 + ck);
    __syncthreads();
    *(uint4*)&As[c0row][ck] = av0;
    *(uint4*)&As[c0row + 32][ck] = av1;
    *(uint4*)&Bs[c0row][ck] = bv0;
    *(uint4*)&Bs[c0row + 32][ck] = bv1;
    __syncthreads();
#pragma unroll
    for (int kk = 0; kk < 2; kk++) {
      short8 af0 = *(const short8*)&As[wr * 32 + lm][kk * 32 + lg * 8];
      short8 af1 = *(const short8*)&As[wr * 32 + 16 + lm][kk * 32 + lg * 8];
      short8 bf0 = *(const short8*)&Bs[wc * 32 + lm][kk * 32 + lg * 8];
      short8 bf1 = *(const short8*)&Bs[wc * 32 + 16 + lm][kk * 32 + lg * 8];
      acc[0][0] = __builtin_amdgcn_mfma_f32_16x16x32_bf16(af0, bf0, acc[0][0], 0, 0, 0);
      acc[0][1] = __builtin_amdgcn_mfma_f32_16x16x32_bf16(af0, bf1, acc[0][1], 0, 0, 0);
      acc[1][0] = __builtin_amdgcn_mfma_f32_16x16x32_bf16(af1, bf0, acc[1][0], 0, 0, 0);
      acc[1][1] = __builtin_amdgcn_mfma_f32_16x16x32_bf16(af1, bf1, acc[1][1], 0, 0, 0);
    }
  }
#pragma unroll
  for (int mf = 0; mf < 2; mf++)
#pragma unroll
    for (int nf = 0; nf < 2; nf++) {
      int col = bn * 64 + wc * 32 + nf * 16 + lm;
      float bb = bias[col];
      int base = bm * 64 + wr * 32 + mf * 16 + lg * 4;
      int mcur = base / 46;
      float s = 0.f;
#pragma unroll
      for (int r = 0; r < 4; r++) {
        float v = fmaxf(acc[mf][nf][r] + bb, 0.f) * (1.0f / 46.0f);
        int mm = (base + r) / 46;
        if (mm != mcur) { atomicAdd(&mc[mcur * FNUM + col], s); s = 0.f; mcur = mm; }
        s += v;
      }
      atomicAdd(&mc[mcur * FNUM + col], s);
    }
}

// ---------------------------------------------------------------------------
// device bodies for the MEGA-MID kernel
__device__ __forceinline__ void conv_ms_body(
    const float* __restrict__ msg, const float* __restrict__ WT,
    const float* __restrict__ B, float* __restrict__ ms, int b) {
  int m = b / 3, fi = b - m * 3;
  int f = fi * 256 + threadIdx.x;
  const float* x = msg + m * SURF_LL * DDIM;
  float a0 = 0.f, a1 = 0.f, a2 = 0.f;
  for (int d = 0; d < DDIM; d++) {
    float v0 = x[d], v1 = x[DDIM + d], v2 = x[2 * DDIM + d], v3 = x[3 * DDIM + d];
    float wA = WT[(size_t)(2 * d) * FNUM + f];
    float wB = WT[(size_t)(2 * d + 1) * FNUM + f];
    a0 += v0 * wA + v1 * wB;
    a1 += v1 * wA + v2 * wB;
    a2 += v2 * wA + v3 * wB;
  }
  float bb = B[f];
  float r = fmaxf(a0 + bb, 0.f) + fmaxf(a1 + bb, 0.f) + fmaxf(a2 + bb, 0.f);
  ms[m * FNUM + f] = r * (1.0f / 3.0f);
}

// PV over the resident 100-row K tile; P (normalized, in acc slots S0/S1,
// lane=k layout: k_rel = lane for S0, lane+64 (lane<36) for S1) goes through
// a chunked wave-private LDS buffer Pl[32][52] overlaying dead Qs.
// Chunk A: k_rel 0..51; chunk B: k_rel 52..99 -> cols 0..47.
// Same-wave DS ordering makes the A-read/B-write overlap safe (R4-validated).
#define PV_TILE(S0, S1)                                                       \
  {                                                                           \
    if (lane < 52) {                                                          \
      _Pragma("unroll") for (int i = 0; i < 8; i++)                           \
          Pl[(w * 8 + i) * 52 + lane] = acc[i][S0];                           \
    }                                                                         \
    _Pragma("unroll 4") for (int k4 = 0; k4 < 13; k4++) {                     \
      float kv0 = Ks[(k4 * 4 + 0) * 62 + dl];                                 \
      float kv1 = Ks[(k4 * 4 + 1) * 62 + dl];                                 \
      float kv2 = Ks[(k4 * 4 + 2) * 62 + dl];                                 \
      float kv3 = Ks[(k4 * 4 + 3) * 62 + dl];                                 \
      _Pragma("unroll") for (int i = 0; i < 8; i++) {                         \
        float4 pq = *(const float4*)&Pl[(w * 8 + i) * 52 + k4 * 4];           \
        O[i] += pq.x * kv0 + pq.y * kv1 + pq.z * kv2 + pq.w * kv3;            \
      }                                                                       \
    }                                                                         \
    if (lane >= 52) {                                                         \
      _Pragma("unroll") for (int i = 0; i < 8; i++)                           \
          Pl[(w * 8 + i) * 52 + (lane - 52)] = acc[i][S0];                    \
    }                                                                         \
    if (k1ok) {                                                               \
      _Pragma("unroll") for (int i = 0; i < 8; i++)                           \
          Pl[(w * 8 + i) * 52 + (lane + 12)] = acc[i][S1];                    \
    }                                                                         \
    _Pragma("unroll 4") for (int k4 = 0; k4 < 12; k4++) {                     \
      float kv0 = Ks[(52 + k4 * 4 + 0) * 62 + dl];                            \
      float kv1 = Ks[(52 + k4 * 4 + 1) * 62 + dl];                            \
      float kv2 = Ks[(52 + k4 * 4 + 2) * 62 + dl];                            \
      float kv3 = Ks[(52 + k4 * 4 + 3) * 62 + dl];                            \
      _Pragma("unroll") for (int i = 0; i < 8; i++) {                         \
        float4 pq = *(const float4*)&Pl[(w * 8 + i) * 52 + k4 * 4];           \
        O[i] += pq.x * kv0 + pq.y * kv1 + pq.z * kv2 + pq.w * kv3;            \
      }                                                                       \
    }                                                                         \
  }

// Attention with 100-row K tiles re-using ONE Ks buffer and single-pass
// softmax (all scores in acc[8][2*NT] regs, R1 structure -> low VGPR).
// dir0 (Lk=200): QK t0 -> restage -> QK t1 -> softmax -> PV t1 (resident)
// -> restage t0 -> PV t0.  dir1 (Lk=100): one tile, no restage.
// smem: Ks 6200 + Qs/Pl overlay 2048 + red 256 = 8504 floats (34 KB)
// -> 4 blocks/CU.  Extra t0 restage is L2-hot (24 KB/block).
template <int DIR>
__device__ __forceinline__ void scores_pv_body(
    const float* __restrict__ embed, const int* __restrict__ doc_vec,
    const int* __restrict__ body_vec, float* __restrict__ pvp, int b,
    float* __restrict__ smem) {
  constexpr int Lq = DIR ? 200 : 100;
  constexpr int NT = DIR ? 1 : 2;    // 100-row k tiles
  constexpr int NS = 2 * NT;         // score slots per q row
  constexpr int NQT = DIR ? 7 : 4;
  int qt = b / 80;
  int rem = b - qt * 80;
  int n = rem / 5, h = rem - n * 5;
  const int* qids = DIR ? body_vec + n * BODY_LL : doc_vec;
  const int* kids = DIR ? doc_vec : body_vec + n * BODY_LL;
  float* Ks = smem;            // [100][62]
  float* Qs = smem + 6200;     // [32][64]  (QK phase)
  float* Pl = smem + 6200;     // [32][52]  (PV phase overlay)
  float* red = smem + 8248;    // [4][64]
  // stage Q + K tile 0 (one barrier covers both)
  for (int idx = threadIdx.x; idx < 32 * 15; idx += 256) {
    int r = idx / 15, c = idx - r * 15;
    int q = qt * 32 + r; if (q >= Lq) q = Lq - 1;
    float4 v = *(const float4*)(embed + (size_t)qids[q] * DDIM + h * HDIM + c * 4);
    float* dp = Qs + r * 64 + c * 4;
    dp[0] = v.x; dp[1] = v.y; dp[2] = v.z; dp[3] = v.w;
  }
  for (int idx = threadIdx.x; idx < 100 * 15; idx += 256) {
    int r = idx / 15, c = idx - r * 15;
    float4 v = *(const float4*)(embed + (size_t)kids[r] * DDIM + h * HDIM + c * 4);
    float* dp = Ks + r * 62 + c * 4;
    dp[0] = v.x; dp[1] = v.y; dp[2] = v.z; dp[3] = v.w;
  }
  __syncthreads();
  int w = threadIdx.x >> 6, lane = threadIdx.x & 63;
  int dl = (lane < HDIM) ? lane : (HDIM - 1);
  int kc0 = lane;                       // k_rel of slot 0 (always < 100)
  bool k1ok = (lane < 36);              // slot 1 valid: k_rel = lane+64 < 100
  int kc1 = k1ok ? lane + 64 : 99;
  float acc[8][NS];
#pragma unroll
  for (int i = 0; i < 8; i++)
#pragma unroll
    for (int j = 0; j < NS; j++) acc[i][j] = 0.f;
  // QK^T tile 0 -> slots 0,1
  for (int d = 0; d < HDIM; d += 4) {
    float2 a0 = *(const float2*)&Ks[kc0 * 62 + d];
    float2 b0 = *(const float2*)&Ks[kc0 * 62 + d + 2];
    float2 a1 = *(const float2*)&Ks[kc1 * 62 + d];
    float2 b1 = *(const float2*)&Ks[kc1 * 62 + d + 2];
#pragma unroll
    for (int i = 0; i < 8; i++) {
      float4 qv = *(const float4*)&Qs[(w * 8 + i) * 64 + d];
      acc[i][0] += qv.x * a0.x + qv.y * a0.y + qv.z * b0.x + qv.w * b0.y;
      acc[i][1] += qv.x * a1.x + qv.y * a1.y + qv.z * b1.x + qv.w * b1.y;
    }
  }
  if constexpr (NT == 2) {
    __syncthreads();  // all waves done reading Ks tile 0
    for (int idx = threadIdx.x; idx < 100 * 15; idx += 256) {
      int r = idx / 15, c = idx - r * 15;
      float4 v = *(const float4*)(embed + (size_t)kids[100 + r] * DDIM + h * HDIM + c * 4);
      float* dp = Ks + r * 62 + c * 4;
      dp[0] = v.x; dp[1] = v.y; dp[2] = v.z; dp[3] = v.w;
    }
    __syncthreads();
    // QK^T tile 1 -> slots 2,3
    for (int d = 0; d < HDIM; d += 4) {
      float2 a0 = *(const float2*)&Ks[kc0 * 62 + d];
      float2 b0 = *(const float2*)&Ks[kc0 * 62 + d + 2];
      float2 a1 = *(const float2*)&Ks[kc1 * 62 + d];
      float2 b1 = *(const float2*)&Ks[kc1 * 62 + d + 2];
#pragma unroll
      for (int i = 0; i < 8; i++) {
        float4 qv = *(const float4*)&Qs[(w * 8 + i) * 64 + d];
        acc[i][NS - 2] += qv.x * a0.x + qv.y * a0.y + qv.z * b0.x + qv.w * b0.y;
        acc[i][NS - 1] += qv.x * a1.x + qv.y * a1.y + qv.z * b1.x + qv.w * b1.y;
      }
    }
  }
  // single-pass softmax in regs (masks: slot1/3 need lane<36); normalized
  // P written back into acc so PV output needs no division.
  const float scale = 0.12909944487358056f;  // 1/sqrt(60)
#pragma unroll
  for (int i = 0; i < 8; i++) {
    float mx = acc[i][0];
    if (k1ok) mx = fmaxf(mx, acc[i][1]);
    if constexpr (NT == 2) {
      mx = fmaxf(mx, acc[i][2]);
      if (k1ok) mx = fmaxf(mx, acc[i][3]);
    }
#pragma unroll
    for (int o = 32; o >= 1; o >>= 1) mx = fmaxf(mx, __shfl_xor(mx, o));
    float mxs = mx * scale;
    float p0 = __expf(acc[i][0] * scale - mxs);
    float p1 = k1ok ? __expf(acc[i][1] * scale - mxs) : 0.f;
    float s = p0 + p1;
    float p2 = 0.f, p3 = 0.f;
    if constexpr (NT == 2) {
      p2 = __expf(acc[i][2] * scale - mxs);
      p3 = k1ok ? __expf(acc[i][3] * scale - mxs) : 0.f;
      s += p2 + p3;
    }
#pragma unroll
    for (int o = 32; o >= 1; o >>= 1) s += __shfl_xor(s, o);
    float inv = 1.0f / s;
    acc[i][0] = p0 * inv;
    acc[i][1] = p1 * inv;
    if constexpr (NT == 2) { acc[i][2] = p2 * inv; acc[i][3] = p3 * inv; }
  }
  __syncthreads();  // all waves done reading Qs -> Pl overlay safe
  float O[8];
#pragma unroll
  for (int i = 0; i < 8; i++) O[i] = 0.f;
  // PV resident tile (tile NT-1): slots NS-2, NS-1
  PV_TILE(NS - 2, NS - 1);
  if constexpr (NT == 2) {
    __syncthreads();  // all waves done reading Ks tile 1
    for (int idx = threadIdx.x; idx < 100 * 15; idx += 256) {
      int r = idx / 15, c = idx - r * 15;
      float4 v = *(const float4*)(embed + (size_t)kids[r] * DDIM + h * HDIM + c * 4);
      float* dp = Ks + r * 62 + c * 4;
      dp[0] = v.x; dp[1] = v.y; dp[2] = v.z; dp[3] = v.w;
    }
    __syncthreads();
    PV_TILE(0, 1);
  }
  // max over this wave's valid q rows (O already normalized)
  float omax = -1e30f;
#pragma unroll
  for (int i = 0; i < 8; i++) {
    int q = qt * 32 + w * 8 + i;
    if (q < Lq) omax = fmaxf(omax, O[i]);
  }
  red[w * 64 + lane] = omax;
  __syncthreads();
  if (threadIdx.x < 64 && lane < HDIM) {
    float m4 = fmaxf(fmaxf(red[0 * 64 + lane], red[1 * 64 + lane]),
                     fmaxf(red[2 * 64 + lane], red[3 * 64 + lane]));
    pvp[((size_t)(n * NHEADS + h) * NQT + qt) * HDIM + lane] = m4;
  }
}

// tok + ctxv fused, one block per m; cand read from global (L2-hot),
// ctx tiles in LDS.  smem use: 5500 floats.
__device__ __forceinline__ void tokctxv_body(
    const float* __restrict__ candg, const float* __restrict__ ctx2g,
    float* __restrict__ local_att, int m, float* __restrict__ smem) {
  float* ctx   = smem;          // [16][300]
  float* tokb  = smem + 4800;   // [16][17]
  float* tkmx  = smem + 5072;   // [64] (50 used)
  float* pp    = smem + 5136;   // [64]
  float* sctxv = smem + 5200;   // [300]
  int tid = threadIdx.x;
  int nI = tid >> 4, tt = tid & 15;
  const float* cand = candg + (size_t)m * NN * DDIM;
  for (int tile = 0; tile < 4; tile++) {
    int cbase = tile * 16;
    __syncthreads();
    for (int i = tid; i < 16 * DDIM; i += 256) {
      int rr = i / DDIM, cc = i - rr * DDIM;
      int t = cbase + rr;
      ctx[rr * DDIM + cc] = (t < CTX_LL) ? ctx2g[(size_t)(m * CTX_LL + t) * DDIM + cc] : 0.f;
    }
    __syncthreads();
    const float4* ca = (const float4*)(cand + nI * DDIM);
    const float4* cb = (const float4*)(ctx + tt * DDIM);
    float dsum = 0.f;
#pragma unroll
    for (int c = 0; c < 75; c++) {
      float4 a = ca[c], b = cb[c];
      dsum += a.x * b.x + a.y * b.y + a.z * b.z + a.w * b.w;
    }
    tokb[nI * 17 + tt] = dsum;
    __syncthreads();
    if (tid < 16) {
      float mx = -1e30f;
      for (int nn = 0; nn < NN; nn++) mx = fmaxf(mx, tokb[nn * 17 + tid]);
      int t = cbase + tid;
      if (t < CTX_LL) tkmx[t] = mx;
    }
  }
  __syncthreads();
  if (tid < 64) {
    float v = (tid < CTX_LL) ? tkmx[tid] : -1e30f;
    float mx = v;
#pragma unroll
    for (int o = 32; o >= 1; o >>= 1) mx = fmaxf(mx, __shfl_xor(mx, o));
    float e = (tid < CTX_LL) ? expf(v - mx) : 0.f;
    float s = e;
#pragma unroll
    for (int o = 32; o >= 1; o >>= 1) s += __shfl_xor(s, o);
    pp[tid] = e / s;
  }
  __syncthreads();
  for (int d = tid; d < DDIM; d += 256) {
    float acc = 0.f;
    for (int t = 0; t < CTX_LL; t++)
      acc += pp[t] * ctx2g[(size_t)(m * CTX_LL + t) * DDIM + d];
    sctxv[d] = acc;
  }
  __syncthreads();
  int j = tid & 15;
  float dd = 0.f;
  for (int i = j; i < DDIM; i += 16) dd += cand[nI * DDIM + i] * sctxv[i];
#pragma unroll
  for (int o = 8; o >= 1; o >>= 1) dd += __shfl_xor(dd, o);
  if (j == 0) local_att[m * NN + nI] = dd;
}

// MEGA-MID: [0,192) conv_ms ; [192,512) attn dir0 ; [512,1072) attn dir1 ;
// [1072,1136) tok+ctxv.  Unified smem 8504 floats (34 KB, 4 blocks/CU);
// no VGPR cap (R2 lesson), single-pass softmax keeps VGPR ~R1 (R4 lesson).
__global__ __launch_bounds__(256) void mega_mid_kernel(
    const float* __restrict__ embed,
    const int* __restrict__ doc_vec,
    const int* __restrict__ body_vec,
    const float* __restrict__ msg,
    const float* __restrict__ WTms,
    const float* __restrict__ Bms,
    const float* __restrict__ candg,
    const float* __restrict__ ctx2g,
    float* __restrict__ ms,
    float* __restrict__ pv0,
    float* __restrict__ pv1,
    float* __restrict__ local_att) {
  __shared__ float smem[8504];
  int bid = blockIdx.x;
  if (bid < 192) {
    conv_ms_body(msg, WTms, Bms, ms, bid);
  } else if (bid < 512) {
    scores_pv_body<0>(embed, doc_vec, body_vec, pv0, bid - 192, smem);
  } else if (bid < 1072) {
    scores_pv_body<1>(embed, doc_vec, body_vec, pv1, bid - 512, smem);
  } else {
    tokctxv_body(candg, ctx2g, local_att, bid - 1072, smem);
  }
}

// ---------------------------------------------------------------------------
// MLP: 80 blocks = 16 n x 5 j-chunks of 60.  Each block: build comb[600]
// (max over qt partials), k-split across 4 waves, LDS-reduce, relu, dot w2,
// atomicAdd pre-sigmoid logit.  Sigmoid applied in final_kernel.
__global__ __launch_bounds__(256) void mlp_kernel(
    const float* __restrict__ pv0, const float* __restrict__ pv1,
    const float* __restrict__ w1, const float* __restrict__ b1,
    const float* __restrict__ w2,
    float* __restrict__ att_logit) {
  int bid = blockIdx.x;
  int n = bid / 5, jc = bid - n * 5;
  int tid = threadIdx.x;
  __shared__ float comb[600];
  __shared__ float partial[4][64];
  for (int idx = tid; idx < 600; idx += 256) {
    int side = idx >= 300;
    int pos = idx - side * 300;
    int h = pos / 60, d = pos - h * 60;
    float mx = -1e30f;
    if (!side) {
#pragma unroll
      for (int pt = 0; pt < 4; pt++)
        mx = fmaxf(mx, pv0[(size_t)((n * NHEADS + h) * 4 + pt) * HDIM + d]);
    } else {
#pragma unroll
      for (int pt = 0; pt < 7; pt++)
        mx = fmaxf(mx, pv1[(size_t)((n * NHEADS + h) * 7 + pt) * HDIM + d]);
    }
    comb[idx] = mx;
  }
  __syncthreads();
  int w = tid >> 6, lane = tid & 63;
  int jl = (lane < 60) ? lane : 59;
  int jg = jc * 60 + jl;
  float acc = 0.f;
  for (int k = w; k < 600; k += 4)
    acc += comb[k] * w1[(size_t)k * 300 + jg];
  partial[w][lane] = acc;
  __syncthreads();
  if (tid < 64) {
    float hv = partial[0][lane] + partial[1][lane] +
               partial[2][lane] + partial[3][lane];
    float hj = fmaxf(hv + b1[jg], 0.f) * w2[jg];
    if (lane >= 60) hj = 0.f;
#pragma unroll
    for (int o = 32; o >= 1; o >>= 1) hj += __shfl_xor(hj, o);
    if (lane == 0) atomicAdd(&att_logit[n], hj);
  }
}

// ---------------------------------------------------------------------------
__global__ __launch_bounds__(256) void final_kernel(
    const float* __restrict__ ms,
    const float* __restrict__ mc,
    const float* __restrict__ title,
    const float* __restrict__ bert,
    const float* __restrict__ att_logit,
    const float* __restrict__ b2,
    const float* __restrict__ m2c_prior,
    const float* __restrict__ hand,
    const float* __restrict__ local_att,
    const float* __restrict__ w7,
    const float* __restrict__ b7,
    float* __restrict__ out) {
  int m = blockIdx.x, tid = threadIdx.x;
  __shared__ float sms[FNUM], smc[FNUM], smd[FNUM];
  __shared__ float snorm[3], sscore[16], wred[3][4];
  for (int i = tid; i < FNUM; i += 256) {
    sms[i] = ms[m * FNUM + i];
    smc[i] = mc[m * FNUM + i];
    smd[i] = bert[i];
  }
  __syncthreads();
  float p1 = 0.f, p2 = 0.f, p3 = 0.f;
  for (int i = tid; i < FNUM; i += 256) {
    float a = sms[i], b = smc[i], c = smd[i];
    p1 += a * a; p2 += b * b; p3 += c * c;
  }
#pragma unroll
  for (int o = 32; o >= 1; o >>= 1) {
    p1 += __shfl_xor(p1, o); p2 += __shfl_xor(p2, o); p3 += __shfl_xor(p3, o);
  }
  int wid = tid >> 6, lane = tid & 63;
  if (lane == 0) { wred[0][wid] = p1; wred[1][wid] = p2; wred[2][wid] = p3; }
  __syncthreads();
  if (tid == 0) {
    snorm[0] = fmaxf(sqrtf(wred[0][0] + wred[0][1] + wred[0][2] + wred[0][3]), 1e-6f);
    snorm[1] = fmaxf(sqrtf(wred[1][0] + wred[1][1] + wred[1][2] + wred[1][3]), 1e-6f);
    snorm[2] = fmaxf(sqrtf(wred[2][0] + wred[2][1] + wred[2][2] + wred[2][3]), 1e-6f);
  }
  __syncthreads();
  int nI = tid >> 4, j = tid & 15;
  float d1 = 0.f, d2 = 0.f, d3 = 0.f, d4 = 0.f;
  for (int i = j; i < FNUM; i += 16) {
    float t = title[nI * FNUM + i];
    d1 += sms[i] * t; d2 += smc[i] * t; d3 += smd[i] * t; d4 += t * t;
  }
#pragma unroll
  for (int o = 8; o >= 1; o >>= 1) {
    d1 += __shfl_xor(d1, o); d2 += __shfl_xor(d2, o);
    d3 += __shfl_xor(d3, o); d4 += __shfl_xor(d4, o);
  }
  if (j == 0) {
    float nt = fmaxf(sqrtf(d4), 1e-6f);
    float cos_st = d1 / (snorm[0] * nt);
    float cos_ct = d2 / (snorm[1] * nt);
    float cos_dt = d3 / (snorm[2] * nt);
    float asc = 1.0f / (1.0f + expf(-(att_logit[nI] + b2[0])));
    float score = hand[nI] * w7[0] + m2c_prior[nI] * w7[1] +
                  local_att[m * NN + nI] * w7[2] + asc * w7[3] +
                  cos_st * w7[4] + cos_dt * w7[5] + cos_ct * w7[6] + b7[0];
    sscore[nI] = score;
  }
  __syncthreads();
  if (tid < 16) {
    float x = sscore[tid];
    float s = x;
#pragma unroll
    for (int o = 8; o >= 1; o >>= 1) s += __shfl_xor(s, o);
    float mu = s * (1.0f / 16.0f);
    float dv = (x - mu) * (x - mu);
    float vs = dv;
#pragma unroll
    for (int o = 8; o >= 1; o >>= 1) vs += __shfl_xor(vs, o);
    float sd = sqrtf(vs * (1.0f / 15.0f));
    float z = (x - mu) / sd;
    float zm = z;
#pragma unroll
    for (int o = 8; o >= 1; o >>= 1) zm = fmaxf(zm, __shfl_xor(zm, o));
    float e = expf(z - zm);
    float es = e;
#pragma unroll
    for (int o = 8; o >= 1; o >>= 1) es += __shfl_xor(es, o);
    float sm = e / es;
    float zmin = z;
#pragma unroll
    for (int o = 8; o >= 1; o >>= 1) zmin = fminf(zmin, __shfl_xor(zmin, o));
    float u0 = (z + 1.0f - zmin) / (zm - zmin);
    float us = u0;
#pragma unroll
    for (int o = 8; o >= 1; o >>= 1) us += __shfl_xor(us, o);
    float u = u0 / us;
    out[m * NN + tid] = z;
    out[MM * NN + m * NN + tid] = sm;
    out[2 * MM * NN + m * NN + tid] = u;
  }
}

// ---------------------------------------------------------------------------
extern "C" void kernel_launch(void* const* d_in, const int* in_sizes, int n_in,
                              void* d_out, int out_size, void* d_ws, size_t ws_size,
                              hipStream_t stream) {
  const int*   mention_vec   = (const int*)d_in[3];
  const int*   context_vec   = (const int*)d_in[4];
  const int*   doc_vec       = (const int*)d_in[5];
  const float* title_vec     = (const float*)d_in[6];
  const int*   body_vec      = (const int*)d_in[7];
  const float* m2c_prior     = (const float*)d_in[9];
  const int*   men2cands     = (const int*)d_in[10];
  const int*   contexts_ids  = (const int*)d_in[11];
  const float* hand_features = (const float*)d_in[12];
  const float* bert_doc_vec  = (const float*)d_in[13];
  const float* embed_table   = (const float*)d_in[14];
  const float* conv_ms_w     = (const float*)d_in[15];
  const float* conv_ms_b     = (const float*)d_in[16];
  const float* conv_mc_w     = (const float*)d_in[17];
  const float* conv_mc_b     = (const float*)d_in[18];
  const float* layer_local_w = (const float*)d_in[19];
  const float* layer_local_b = (const float*)d_in[20];
  const float* att_w1        = (const float*)d_in[21];
  const float* att_b1        = (const float*)d_in[22];
  const float* att_w2        = (const float*)d_in[23];
  const float* att_b2        = (const float*)d_in[24];

  float* ws     = (float*)d_ws;
  float* msg    = ws + OFF_MSG;
  float* ctx2g  = ws + OFF_CTX2G;
  float* candg  = ws + OFF_CANDG;
  float* ms     = ws + OFF_MS;
  float* mc     = ws + OFF_MC;
  float* pv0    = ws + OFF_PV0;
  float* pv1    = ws + OFF_PV1;
  float* att_lg = ws + OFF_ASC;
  float* latt   = ws + OFF_LATT;
  u16*   Abf    = (u16*)(ws + OFF_ABF);
  u16*   WTmc   = (u16*)(ws + OFF_WTMC);
  float* WTms   = ws + OFF_WTMS;
  float* out    = (float*)d_out;

  mega_prep_kernel<<<dim3(18379), dim3(256), 0, stream>>>(
      embed_table, mention_vec, context_vec, contexts_ids, men2cands,
      conv_mc_w, conv_ms_w, ws, mc, att_lg, (u32*)Abf, (u32*)WTmc, WTms);
  conv_gemm_kernel<<<dim3(GN / 64, GM / 64), dim3(256), 0, stream>>>(
      Abf, WTmc, conv_mc_b, mc);
  mega_mid_kernel<<<dim3(1136), dim3(256), 0, stream>>>(
      embed_table, doc_vec, body_vec, msg, WTms, conv_ms_b, candg, ctx2g,
      ms, pv0, pv1, latt);
  mlp_kernel<<<dim3(80), dim3(256), 0, stream>>>(
      pv0, pv1, att_w1, att_b1, att_w2, att_lg);
  final_kernel<<<dim3(MM), dim3(256), 0, stream>>>(
      ms, mc, title_vec, bert_doc_vec, att_lg, att_b2, m2c_prior,
      hand_features, latt, layer_local_w, layer_local_b, out);
}

// Round 6
// 375.768 us; speedup vs baseline: 1.2047x; 1.2047x over previous
//
#include <hip/hip_runtime.h>

#define MM 64
#define NN 16
#define DDIM 300
#define FNUM 768
#define SURF_LL 4
#define CTX_LL 50
#define DOC_LL 100
#define BODY_LL 200
#define NHEADS 5
#define HDIM 60

// GEMM dims for conv_mc:  C[GM][GN] = A[GM][GK] * B^T, K padded 1500->1536
#define GM 2944   // 64 m * 46 t
#define GK 1536
#define GN 768

typedef unsigned short u16;
typedef unsigned int u32;
typedef __attribute__((ext_vector_type(8))) short short8;
typedef __attribute__((ext_vector_type(4))) float f32x4;

// ---- workspace layout (float offsets) ----
#define OFF_MSG    0                    // mention emb [256][300]
#define OFF_CTX2G  76800                // contexts_ids emb [3200][300]
#define OFF_CANDG  1036800              // men2cands emb [1024][300]
#define OFF_MS     1344000              // ms [64][768]
#define OFF_MC     1393152              // mc [64][768] (atomic mean accum)
#define OFF_PV0    1442304              // [16][5][4][60] per-qt partial max
#define OFF_PV1    1461504              // [16][5][7][60] per-qt partial max
#define OFF_ASC    1495104              // att logit [16] (atomic accum)
#define OFF_LATT   1495120              // [64][16]
#define OFF_ABF    1496144              // u16[GM*GK]
#define OFF_WTMC   (OFF_ABF + GM*GK/2)  // u16[GN*GK]
#define OFF_WTMS   (OFF_WTMC + GN*GK/2) // float[600*768]

__device__ __forceinline__ u16 f2bf(float x) {
  union { float f; u32 u; } v; v.f = x;
  u32 r = v.u + 0x7FFFu + ((v.u >> 16) & 1u);
  return (u16)(r >> 16);
}

// ---------------------------------------------------------------------------
// MEGA-PREP: gather embeddings + zero mc + zero att logit + im2col bf16 +
// weight repacks.
// blocks: [0,5250) gather ; [5250,5442) mc zero ; 5442 logit zero ;
//         [5443,14275) abuild ; [14275,16579) wtmc ; [16579,18379) wtms
__global__ __launch_bounds__(256) void mega_prep_kernel(
    const float* __restrict__ embed,
    const int* __restrict__ mention_vec,
    const int* __restrict__ context_vec,
    const int* __restrict__ contexts_ids,
    const int* __restrict__ men2cands,
    const float* __restrict__ Wmc,
    const float* __restrict__ Wms,
    float* __restrict__ dst, float* __restrict__ mc,
    float* __restrict__ att_logit,
    u32* __restrict__ Abf, u32* __restrict__ WTmc, float* __restrict__ WTms) {
  int bid = blockIdx.x;
  if (bid < 5250) {
    int e = bid * 256 + threadIdx.x;
    int row = e / DDIM;
    int col = e - row * DDIM;
    int tok;
    if (row < 256)       tok = mention_vec[row];
    else if (row < 3456) tok = contexts_ids[row - 256];
    else                 tok = men2cands[row - 3456];
    dst[e] = embed[(size_t)tok * DDIM + col];
  } else if (bid < 5442) {
    mc[(bid - 5250) * 256 + threadIdx.x] = 0.f;
  } else if (bid == 5442) {
    if (threadIdx.x < NN) att_logit[threadIdx.x] = 0.f;
  } else if (bid < 14275) {
    int idx = (bid - 5443) * 256 + threadIdx.x;  // one u32 = 2 bf16
    int r = idx / (GK / 2);
    int kp = idx - r * (GK / 2);
    int k = kp * 2;
    int m = r / 46, t = r - m * 46;
    u32 out = 0;
#pragma unroll
    for (int j = 0; j < 2; j++) {
      int kj = k + j;
      u16 h = 0;
      if (kj < 1500) {
        int tap = kj / 300;
        int d = kj - tap * 300;
        int tok = context_vec[m * CTX_LL + t + tap];
        h = f2bf(embed[(size_t)tok * DDIM + d]);
      }
      out |= (u32)h << (16 * j);
    }
    Abf[idx] = out;
  } else if (bid < 16579) {
    int idx = (bid - 14275) * 256 + threadIdx.x;
    int n = idx / (GK / 2);
    int kp = idx - n * (GK / 2);
    int k = kp * 2;
    u32 out = 0;
#pragma unroll
    for (int j = 0; j < 2; j++) {
      int kj = k + j;
      u16 h = 0;
      if (kj < 1500) {
        int tap = kj / 300;
        int d = kj - tap * 300;
        h = f2bf(Wmc[(size_t)n * 1500 + d * 5 + tap]);
      }
      out |= (u32)h << (16 * j);
    }
    WTmc[idx] = out;
  } else {
    int idx = (bid - 16579) * 256 + threadIdx.x;  // 600*768
    int k = idx / FNUM;
    int f = idx - k * FNUM;
    WTms[idx] = Wms[(size_t)f * 600 + k];
  }
}

// ---------------------------------------------------------------------------
// bf16 MFMA GEMM body with fused relu+mean epilogue (atomicAdd into mc).
// As/Bs carved from the unified smem buffer (2304 floats each as u16[64][72]).
__device__ __forceinline__ void conv_gemm_body(
    const u16* __restrict__ A,    // [GM][GK] bf16
    const u16* __restrict__ B,    // [GN][GK] bf16 (n-major)
    const float* __restrict__ bias,
    float* __restrict__ mc, int g, float* __restrict__ smem) {
  int bn = g % (GN / 64), bm = g / (GN / 64);
  u16* As = (u16*)smem;            // [64][72]
  u16* Bs = (u16*)(smem + 2304);   // [64][72]
  int tid = threadIdx.x;
  int w = tid >> 6, lane = tid & 63;
  int wr = w >> 1, wc = w & 1;
  int lg = lane >> 4, lm = lane & 15;
  f32x4 acc[2][2];
#pragma unroll
  for (int i = 0; i < 2; i++)
#pragma unroll
    for (int j = 0; j < 2; j++) acc[i][j] = (f32x4)0.f;
  int c0row = tid >> 3, ck = (tid & 7) * 8;
  const u16* Ag = A + (size_t)(bm * 64) * GK;
  const u16* Bg = B + (size_t)(bn * 64) * GK;
  for (int kt = 0; kt < GK / 64; kt++) {
    int k0 = kt * 64;
    uint4 av0 = *(const uint4*)(Ag + (size_t)c0row * GK + k0 + ck);
    uint4 av1 = *(const uint4*)(Ag + (size_t)(c0row + 32) * GK + k0 + ck);
    uint4 bv0 = *(const uint4*)(Bg + (size_t)c0row * GK + k0 + ck);
    uint4 bv1 = *(const uint4*)(Bg + (size_t)(c0row + 32) * GK + k0 + ck);
    __syncthreads();
    *(uint4*)&As[c0row * 72 + ck] = av0;
    *(uint4*)&As[(c0row + 32) * 72 + ck] = av1;
    *(uint4*)&Bs[c0row * 72 + ck] = bv0;
    *(uint4*)&Bs[(c0row + 32) * 72 + ck] = bv1;
    __syncthreads();
#pragma unroll
    for (int kk = 0; kk < 2; kk++) {
      short8 af0 = *(const short8*)&As[(wr * 32 + lm) * 72 + kk * 32 + lg * 8];
      short8 af1 = *(const short8*)&As[(wr * 32 + 16 + lm) * 72 + kk * 32 + lg * 8];
      short8 bf0 = *(const short8*)&Bs[(wc * 32 + lm) * 72 + kk * 32 + lg * 8];
      short8 bf1 = *(const short8*)&Bs[(wc * 32 + 16 + lm) * 72 + kk * 32 + lg * 8];
      acc[0][0] = __builtin_amdgcn_mfma_f32_16x16x32_bf16(af0, bf0, acc[0][0], 0, 0, 0);
      acc[0][1] = __builtin_amdgcn_mfma_f32_16x16x32_bf16(af0, bf1, acc[0][1], 0, 0, 0);
      acc[1][0] = __builtin_amdgcn_mfma_f32_16x16x32_bf16(af1, bf0, acc[1][0], 0, 0, 0);
      acc[1][1] = __builtin_amdgcn_mfma_f32_16x16x32_bf16(af1, bf1, acc[1][1], 0, 0, 0);
    }
  }
#pragma unroll
  for (int mf = 0; mf < 2; mf++)
#pragma unroll
    for (int nf = 0; nf < 2; nf++) {
      int col = bn * 64 + wc * 32 + nf * 16 + lm;
      float bb = bias[col];
      int base = bm * 64 + wr * 32 + mf * 16 + lg * 4;
      int mcur = base / 46;
      float s = 0.f;
#pragma unroll
      for (int r = 0; r < 4; r++) {
        float v = fmaxf(acc[mf][nf][r] + bb, 0.f) * (1.0f / 46.0f);
        int mm = (base + r) / 46;
        if (mm != mcur) { atomicAdd(&mc[mcur * FNUM + col], s); s = 0.f; mcur = mm; }
        s += v;
      }
      atomicAdd(&mc[mcur * FNUM + col], s);
    }
}

// ---------------------------------------------------------------------------
// device bodies for the MEGA-MID kernel (Round-1 validated versions)
__device__ __forceinline__ void conv_ms_body(
    const float* __restrict__ msg, const float* __restrict__ WT,
    const float* __restrict__ B, float* __restrict__ ms, int b) {
  int m = b / 3, fi = b - m * 3;
  int f = fi * 256 + threadIdx.x;
  const float* x = msg + m * SURF_LL * DDIM;
  float a0 = 0.f, a1 = 0.f, a2 = 0.f;
  for (int d = 0; d < DDIM; d++) {
    float v0 = x[d], v1 = x[DDIM + d], v2 = x[2 * DDIM + d], v3 = x[3 * DDIM + d];
    float wA = WT[(size_t)(2 * d) * FNUM + f];
    float wB = WT[(size_t)(2 * d + 1) * FNUM + f];
    a0 += v0 * wA + v1 * wB;
    a1 += v1 * wA + v2 * wB;
    a2 += v2 * wA + v3 * wB;
  }
  float bb = B[f];
  float r = fmaxf(a0 + bb, 0.f) + fmaxf(a1 + bb, 0.f) + fmaxf(a2 + bb, 0.f);
  ms[m * FNUM + f] = r * (1.0f / 3.0f);
}

// Fused flash-attention block (Round-1 validated, 78.4us): QK^T + softmax +
// PV + q-maxpool.  K tile in LDS is also V.  P tile overlays dead Qs
// (wave-private rows).  smem: Ks 12400 + Qs/Pl 3200 + red 256 = 15856.
template <int DIR>
__device__ __forceinline__ void scores_pv_body(
    const float* __restrict__ embed, const int* __restrict__ doc_vec,
    const int* __restrict__ body_vec, float* __restrict__ pvp, int b,
    float* __restrict__ smem) {
  constexpr int Lq = DIR ? 200 : 100;
  constexpr int Lk = DIR ? 100 : 200;
  constexpr int KPL = DIR ? 2 : 4;
  constexpr int NQT = DIR ? 7 : 4;
  constexpr int NHALF = DIR ? 1 : 2;
  int qt = b / 80;
  int rem = b - qt * 80;
  int n = rem / 5, h = rem - n * 5;
  const int* qids = DIR ? body_vec + n * BODY_LL : doc_vec;
  const int* kids = DIR ? doc_vec : body_vec + n * BODY_LL;
  float* Ks = smem;              // [Lk][62]
  float* Qs = smem + 12400;      // [32][64]   (scores phase)
  float* Pl = smem + 12400;      // [32][100]  (PV phase, overlays Qs)
  float* red = smem + 15600;     // [4][64]
  for (int idx = threadIdx.x; idx < Lk * 15; idx += 256) {
    int r = idx / 15, c = idx - r * 15;
    float4 v = *(const float4*)(embed + (size_t)kids[r] * DDIM + h * HDIM + c * 4);
    float* dp = Ks + r * 62 + c * 4;
    dp[0] = v.x; dp[1] = v.y; dp[2] = v.z; dp[3] = v.w;
  }
  for (int idx = threadIdx.x; idx < 32 * 15; idx += 256) {
    int r = idx / 15, c = idx - r * 15;
    int q = qt * 32 + r; if (q >= Lq) q = Lq - 1;
    float4 v = *(const float4*)(embed + (size_t)qids[q] * DDIM + h * HDIM + c * 4);
    float* dp = Qs + r * 64 + c * 4;
    dp[0] = v.x; dp[1] = v.y; dp[2] = v.z; dp[3] = v.w;
  }
  __syncthreads();
  int w = threadIdx.x >> 6, lane = threadIdx.x & 63;
  int kcl[KPL];
#pragma unroll
  for (int j = 0; j < KPL; j++) {
    int kk = lane + 64 * j; kcl[j] = (kk < Lk) ? kk : (Lk - 1);
  }
  float acc[8][KPL];
#pragma unroll
  for (int i = 0; i < 8; i++)
#pragma unroll
    for (int j = 0; j < KPL; j++) acc[i][j] = 0.f;
  for (int d = 0; d < HDIM; d += 4) {
    float2 kva[KPL], kvb[KPL];
#pragma unroll
    for (int j = 0; j < KPL; j++) {
      kva[j] = *(const float2*)&Ks[kcl[j] * 62 + d];
      kvb[j] = *(const float2*)&Ks[kcl[j] * 62 + d + 2];
    }
#pragma unroll
    for (int i = 0; i < 8; i++) {
      float4 qv = *(const float4*)&Qs[(w * 8 + i) * 64 + d];
#pragma unroll
      for (int j = 0; j < KPL; j++)
        acc[i][j] += qv.x * kva[j].x + qv.y * kva[j].y +
                     qv.z * kvb[j].x + qv.w * kvb[j].y;
    }
  }
  const float scale = 0.12909944487358056f;  // 1/sqrt(60)
#pragma unroll
  for (int i = 0; i < 8; i++) {
    float mx = -1e30f;
#pragma unroll
    for (int j = 0; j < KPL; j++)
      if (lane + 64 * j < Lk) mx = fmaxf(mx, acc[i][j]);
#pragma unroll
    for (int o = 32; o >= 1; o >>= 1) mx = fmaxf(mx, __shfl_xor(mx, o));
    float mxs = mx * scale;
    float p[KPL];
    float s = 0.f;
#pragma unroll
    for (int j = 0; j < KPL; j++) {
      p[j] = (lane + 64 * j < Lk) ? __expf(acc[i][j] * scale - mxs) : 0.f;
      s += p[j];
    }
#pragma unroll
    for (int o = 32; o >= 1; o >>= 1) s += __shfl_xor(s, o);
    float inv = 1.0f / s;
#pragma unroll
    for (int j = 0; j < KPL; j++) acc[i][j] = p[j] * inv;  // normalized P in regs
  }
  // all waves done reading Qs before P overlays it
  __syncthreads();
  float o[8];
#pragma unroll
  for (int i = 0; i < 8; i++) o[i] = 0.f;
  int dl = (lane < HDIM) ? lane : (HDIM - 1);
#pragma unroll
  for (int half = 0; half < NHALF; half++) {
    int kbase = half * 100;
    // store this half's P entries (rows 8w..8w+7 are wave-private)
#pragma unroll
    for (int j = 0; j < KPL; j++) {
      int kk = lane + 64 * j;
      int rel = kk - kbase;
      if (rel >= 0 && rel < 100 && kk < Lk) {
#pragma unroll
        for (int i = 0; i < 8; i++)
          Pl[(w * 8 + i) * 100 + rel] = acc[i][j];
      }
    }
    // PV over this half's 100 k values (lane = output dim d)
    for (int k4 = 0; k4 < 25; k4++) {
      int k = kbase + k4 * 4;
      float kv0 = Ks[(k + 0) * 62 + dl];
      float kv1 = Ks[(k + 1) * 62 + dl];
      float kv2 = Ks[(k + 2) * 62 + dl];
      float kv3 = Ks[(k + 3) * 62 + dl];
#pragma unroll
      for (int i = 0; i < 8; i++) {
        float4 pq = *(const float4*)&Pl[(w * 8 + i) * 100 + k4 * 4];
        o[i] += pq.x * kv0 + pq.y * kv1 + pq.z * kv2 + pq.w * kv3;
      }
    }
  }
  // max over this wave's valid q rows
  float omax = -1e30f;
#pragma unroll
  for (int i = 0; i < 8; i++) {
    int q = qt * 32 + w * 8 + i;
    if (q < Lq) omax = fmaxf(omax, o[i]);
  }
  red[w * 64 + lane] = omax;
  __syncthreads();
  if (threadIdx.x < 64 && lane < HDIM) {
    float m4 = fmaxf(fmaxf(red[0 * 64 + lane], red[1 * 64 + lane]),
                     fmaxf(red[2 * 64 + lane], red[3 * 64 + lane]));
    pvp[((size_t)(n * NHEADS + h) * NQT + qt) * HDIM + lane] = m4;
  }
}

// tok + ctxv fused (Round-1 validated), one block per m.
__device__ __forceinline__ void tokctxv_body(
    const float* __restrict__ candg, const float* __restrict__ ctx2g,
    float* __restrict__ local_att, int m, float* __restrict__ smem) {
  float* cand  = smem;          // [16][300]
  float* ctx   = smem + 4800;   // [16][300]
  float* tokb  = smem + 9600;   // [16][17]
  float* tkmx  = smem + 9872;   // [64] (50 used)
  float* pp    = smem + 9936;   // [64]
  float* sctxv = smem + 10000;  // [300]
  int tid = threadIdx.x;
  for (int i = tid; i < NN * DDIM; i += 256)
    cand[i] = candg[(size_t)m * NN * DDIM + i];
  int nI = tid >> 4, tt = tid & 15;
  for (int tile = 0; tile < 4; tile++) {
    int cbase = tile * 16;
    __syncthreads();
    for (int i = tid; i < 16 * DDIM; i += 256) {
      int rr = i / DDIM, cc = i - rr * DDIM;
      int t = cbase + rr;
      ctx[rr * DDIM + cc] = (t < CTX_LL) ? ctx2g[(size_t)(m * CTX_LL + t) * DDIM + cc] : 0.f;
    }
    __syncthreads();
    const float4* ca = (const float4*)(cand + nI * DDIM);
    const float4* cb = (const float4*)(ctx + tt * DDIM);
    float dsum = 0.f;
#pragma unroll
    for (int c = 0; c < 75; c++) {
      float4 a = ca[c], b = cb[c];
      dsum += a.x * b.x + a.y * b.y + a.z * b.z + a.w * b.w;
    }
    tokb[nI * 17 + tt] = dsum;
    __syncthreads();
    if (tid < 16) {
      float mx = -1e30f;
      for (int nn = 0; nn < NN; nn++) mx = fmaxf(mx, tokb[nn * 17 + tid]);
      int t = cbase + tid;
      if (t < CTX_LL) tkmx[t] = mx;
    }
  }
  __syncthreads();
  if (tid < 64) {
    float v = (tid < CTX_LL) ? tkmx[tid] : -1e30f;
    float mx = v;
#pragma unroll
    for (int o = 32; o >= 1; o >>= 1) mx = fmaxf(mx, __shfl_xor(mx, o));
    float e = (tid < CTX_LL) ? expf(v - mx) : 0.f;
    float s = e;
#pragma unroll
    for (int o = 32; o >= 1; o >>= 1) s += __shfl_xor(s, o);
    pp[tid] = e / s;
  }
  __syncthreads();
  for (int d = tid; d < DDIM; d += 256) {
    float acc = 0.f;
    for (int t = 0; t < CTX_LL; t++)
      acc += pp[t] * ctx2g[(size_t)(m * CTX_LL + t) * DDIM + d];
    sctxv[d] = acc;
  }
  __syncthreads();
  int j = tid & 15;
  float dd = 0.f;
  for (int i = j; i < DDIM; i += 16) dd += cand[nI * DDIM + i] * sctxv[i];
#pragma unroll
  for (int o = 8; o >= 1; o >>= 1) dd += __shfl_xor(dd, o);
  if (j == 0) local_att[m * NN + nI] = dd;
}

// MEGA-MID+GEMM: [0,192) conv_ms ; [192,512) attn dir0 ; [512,1072) attn
// dir1 ; [1072,1136) tok+ctxv ; [1136,1688) conv_gemm.  Unified smem 15856
// floats (63.4 KB, 2 blocks/CU).  GEMM blocks last: their MFMA work
// co-schedules on the idle matrix pipe while attn waves stall on
// VALU/LDS (m114: separate pipes overlap fully).
__global__ __launch_bounds__(256) void mega_mid_kernel(
    const float* __restrict__ embed,
    const int* __restrict__ doc_vec,
    const int* __restrict__ body_vec,
    const float* __restrict__ msg,
    const float* __restrict__ WTms,
    const float* __restrict__ Bms,
    const float* __restrict__ candg,
    const float* __restrict__ ctx2g,
    const u16* __restrict__ Abf,
    const u16* __restrict__ WTmc,
    const float* __restrict__ Bmc,
    float* __restrict__ ms,
    float* __restrict__ mc,
    float* __restrict__ pv0,
    float* __restrict__ pv1,
    float* __restrict__ local_att) {
  __shared__ float smem[15856];
  int bid = blockIdx.x;
  if (bid < 192) {
    conv_ms_body(msg, WTms, Bms, ms, bid);
  } else if (bid < 512) {
    scores_pv_body<0>(embed, doc_vec, body_vec, pv0, bid - 192, smem);
  } else if (bid < 1072) {
    scores_pv_body<1>(embed, doc_vec, body_vec, pv1, bid - 512, smem);
  } else if (bid < 1136) {
    tokctxv_body(candg, ctx2g, local_att, bid - 1072, smem);
  } else {
    conv_gemm_body(Abf, WTmc, Bmc, mc, bid - 1136, smem);
  }
}

// ---------------------------------------------------------------------------
// MLP: 80 blocks = 16 n x 5 j-chunks of 60.  Each block: build comb[600]
// (max over qt partials), k-split across 4 waves, LDS-reduce, relu, dot w2,
// atomicAdd pre-sigmoid logit.  Sigmoid applied in final_kernel.
__global__ __launch_bounds__(256) void mlp_kernel(
    const float* __restrict__ pv0, const float* __restrict__ pv1,
    const float* __restrict__ w1, const float* __restrict__ b1,
    const float* __restrict__ w2,
    float* __restrict__ att_logit) {
  int bid = blockIdx.x;
  int n = bid / 5, jc = bid - n * 5;
  int tid = threadIdx.x;
  __shared__ float comb[600];
  __shared__ float partial[4][64];
  for (int idx = tid; idx < 600; idx += 256) {
    int side = idx >= 300;
    int pos = idx - side * 300;
    int h = pos / 60, d = pos - h * 60;
    float mx = -1e30f;
    if (!side) {
#pragma unroll
      for (int pt = 0; pt < 4; pt++)
        mx = fmaxf(mx, pv0[(size_t)((n * NHEADS + h) * 4 + pt) * HDIM + d]);
    } else {
#pragma unroll
      for (int pt = 0; pt < 7; pt++)
        mx = fmaxf(mx, pv1[(size_t)((n * NHEADS + h) * 7 + pt) * HDIM + d]);
    }
    comb[idx] = mx;
  }
  __syncthreads();
  int w = tid >> 6, lane = tid & 63;
  int jl = (lane < 60) ? lane : 59;
  int jg = jc * 60 + jl;
  float acc = 0.f;
  for (int k = w; k < 600; k += 4)
    acc += comb[k] * w1[(size_t)k * 300 + jg];
  partial[w][lane] = acc;
  __syncthreads();
  if (tid < 64) {
    float hv = partial[0][lane] + partial[1][lane] +
               partial[2][lane] + partial[3][lane];
    float hj = fmaxf(hv + b1[jg], 0.f) * w2[jg];
    if (lane >= 60) hj = 0.f;
#pragma unroll
    for (int o = 32; o >= 1; o >>= 1) hj += __shfl_xor(hj, o);
    if (lane == 0) atomicAdd(&att_logit[n], hj);
  }
}

// ---------------------------------------------------------------------------
__global__ __launch_bounds__(256) void final_kernel(
    const float* __restrict__ ms,
    const float* __restrict__ mc,
    const float* __restrict__ title,
    const float* __restrict__ bert,
    const float* __restrict__ att_logit,
    const float* __restrict__ b2,
    const float* __restrict__ m2c_prior,
    const float* __restrict__ hand,
    const float* __restrict__ local_att,
    const float* __restrict__ w7,
    const float* __restrict__ b7,
    float* __restrict__ out) {
  int m = blockIdx.x, tid = threadIdx.x;
  __shared__ float sms[FNUM], smc[FNUM], smd[FNUM];
  __shared__ float snorm[3], sscore[16], wred[3][4];
  for (int i = tid; i < FNUM; i += 256) {
    sms[i] = ms[m * FNUM + i];
    smc[i] = mc[m * FNUM + i];
    smd[i] = bert[i];
  }
  __syncthreads();
  float p1 = 0.f, p2 = 0.f, p3 = 0.f;
  for (int i = tid; i < FNUM; i += 256) {
    float a = sms[i], b = smc[i], c = smd[i];
    p1 += a * a; p2 += b * b; p3 += c * c;
  }
#pragma unroll
  for (int o = 32; o >= 1; o >>= 1) {
    p1 += __shfl_xor(p1, o); p2 += __shfl_xor(p2, o); p3 += __shfl_xor(p3, o);
  }
  int wid = tid >> 6, lane = tid & 63;
  if (lane == 0) { wred[0][wid] = p1; wred[1][wid] = p2; wred[2][wid] = p3; }
  __syncthreads();
  if (tid == 0) {
    snorm[0] = fmaxf(sqrtf(wred[0][0] + wred[0][1] + wred[0][2] + wred[0][3]), 1e-6f);
    snorm[1] = fmaxf(sqrtf(wred[1][0] + wred[1][1] + wred[1][2] + wred[1][3]), 1e-6f);
    snorm[2] = fmaxf(sqrtf(wred[2][0] + wred[2][1] + wred[2][2] + wred[2][3]), 1e-6f);
  }
  __syncthreads();
  int nI = tid >> 4, j = tid & 15;
  float d1 = 0.f, d2 = 0.f, d3 = 0.f, d4 = 0.f;
  for (int i = j; i < FNUM; i += 16) {
    float t = title[nI * FNUM + i];
    d1 += sms[i] * t; d2 += smc[i] * t; d3 += smd[i] * t; d4 += t * t;
  }
#pragma unroll
  for (int o = 8; o >= 1; o >>= 1) {
    d1 += __shfl_xor(d1, o); d2 += __shfl_xor(d2, o);
    d3 += __shfl_xor(d3, o); d4 += __shfl_xor(d4, o);
  }
  if (j == 0) {
    float nt = fmaxf(sqrtf(d4), 1e-6f);
    float cos_st = d1 / (snorm[0] * nt);
    float cos_ct = d2 / (snorm[1] * nt);
    float cos_dt = d3 / (snorm[2] * nt);
    float asc = 1.0f / (1.0f + expf(-(att_logit[nI] + b2[0])));
    float score = hand[nI] * w7[0] + m2c_prior[nI] * w7[1] +
                  local_att[m * NN + nI] * w7[2] + asc * w7[3] +
                  cos_st * w7[4] + cos_dt * w7[5] + cos_ct * w7[6] + b7[0];
    sscore[nI] = score;
  }
  __syncthreads();
  if (tid < 16) {
    float x = sscore[tid];
    float s = x;
#pragma unroll
    for (int o = 8; o >= 1; o >>= 1) s += __shfl_xor(s, o);
    float mu = s * (1.0f / 16.0f);
    float dv = (x - mu) * (x - mu);
    float vs = dv;
#pragma unroll
    for (int o = 8; o >= 1; o >>= 1) vs += __shfl_xor(vs, o);
    float sd = sqrtf(vs * (1.0f / 15.0f));
    float z = (x - mu) / sd;
    float zm = z;
#pragma unroll
    for (int o = 8; o >= 1; o >>= 1) zm = fmaxf(zm, __shfl_xor(zm, o));
    float e = expf(z - zm);
    float es = e;
#pragma unroll
    for (int o = 8; o >= 1; o >>= 1) es += __shfl_xor(es, o);
    float sm = e / es;
    float zmin = z;
#pragma unroll
    for (int o = 8; o >= 1; o >>= 1) zmin = fminf(zmin, __shfl_xor(zmin, o));
    float u0 = (z + 1.0f - zmin) / (zm - zmin);
    float us = u0;
#pragma unroll
    for (int o = 8; o >= 1; o >>= 1) us += __shfl_xor(us, o);
    float u = u0 / us;
    out[m * NN + tid] = z;
    out[MM * NN + m * NN + tid] = sm;
    out[2 * MM * NN + m * NN + tid] = u;
  }
}

// ---------------------------------------------------------------------------
extern "C" void kernel_launch(void* const* d_in, const int* in_sizes, int n_in,
                              void* d_out, int out_size, void* d_ws, size_t ws_size,
                              hipStream_t stream) {
  const int*   mention_vec   = (const int*)d_in[3];
  const int*   context_vec   = (const int*)d_in[4];
  const int*   doc_vec       = (const int*)d_in[5];
  const float* title_vec     = (const float*)d_in[6];
  const int*   body_vec      = (const int*)d_in[7];
  const float* m2c_prior     = (const float*)d_in[9];
  const int*   men2cands     = (const int*)d_in[10];
  const int*   contexts_ids  = (const int*)d_in[11];
  const float* hand_features = (const float*)d_in[12];
  const float* bert_doc_vec  = (const float*)d_in[13];
  const float* embed_table   = (const float*)d_in[14];
  const float* conv_ms_w     = (const float*)d_in[15];
  const float* conv_ms_b     = (const float*)d_in[16];
  const float* conv_mc_w     = (const float*)d_in[17];
  const float* conv_mc_b     = (const float*)d_in[18];
  const float* layer_local_w = (const float*)d_in[19];
  const float* layer_local_b = (const float*)d_in[20];
  const float* att_w1        = (const float*)d_in[21];
  const float* att_b1        = (const float*)d_in[22];
  const float* att_w2        = (const float*)d_in[23];
  const float* att_b2        = (const float*)d_in[24];

  float* ws     = (float*)d_ws;
  float* msg    = ws + OFF_MSG;
  float* ctx2g  = ws + OFF_CTX2G;
  float* candg  = ws + OFF_CANDG;
  float* ms     = ws + OFF_MS;
  float* mc     = ws + OFF_MC;
  float* pv0    = ws + OFF_PV0;
  float* pv1    = ws + OFF_PV1;
  float* att_lg = ws + OFF_ASC;
  float* latt   = ws + OFF_LATT;
  u16*   Abf    = (u16*)(ws + OFF_ABF);
  u16*   WTmc   = (u16*)(ws + OFF_WTMC);
  float* WTms   = ws + OFF_WTMS;
  float* out    = (float*)d_out;

  mega_prep_kernel<<<dim3(18379), dim3(256), 0, stream>>>(
      embed_table, mention_vec, context_vec, contexts_ids, men2cands,
      conv_mc_w, conv_ms_w, ws, mc, att_lg, (u32*)Abf, (u32*)WTmc, WTms);
  mega_mid_kernel<<<dim3(1688), dim3(256), 0, stream>>>(
      embed_table, doc_vec, body_vec, msg, WTms, conv_ms_b, candg, ctx2g,
      Abf, WTmc, conv_mc_b, ms, mc, pv0, pv1, latt);
  mlp_kernel<<<dim3(80), dim3(256), 0, stream>>>(
      pv0, pv1, att_w1, att_b1, att_w2, att_lg);
  final_kernel<<<dim3(MM), dim3(256), 0, stream>>>(
      ms, mc, title_vec, bert_doc_vec, att_lg, att_b2, m2c_prior,
      hand_features, latt, layer_local_w, layer_local_b, out);
}

// Round 7
// 375.701 us; speedup vs baseline: 1.2050x; 1.0002x over previous
//
#include <hip/hip_runtime.h>

#define MM 64
#define NN 16
#define DDIM 300
#define FNUM 768
#define SURF_LL 4
#define CTX_LL 50
#define DOC_LL 100
#define BODY_LL 200
#define NHEADS 5
#define HDIM 60

// GEMM dims for conv_mc:  C[GM][GN] = A[GM][GK] * B^T, K padded 1500->1536
#define GM 2944   // 64 m * 46 t
#define GK 1536
#define GN 768

typedef unsigned short u16;
typedef unsigned int u32;
typedef __attribute__((ext_vector_type(8))) short short8;
typedef __attribute__((ext_vector_type(4))) float f32x4;

// ---- workspace layout (float offsets) ----
#define OFF_MSG    0                    // mention emb [256][300]
#define OFF_CTX2G  76800                // contexts_ids emb [3200][300]
#define OFF_CANDG  1036800              // men2cands emb [1024][300]
#define OFF_MS     1344000              // ms [64][768]
#define OFF_MC     1393152              // mc [64][768] (atomic mean accum)
#define OFF_PV0    1442304              // [16][5][4][60] per-qt partial max
#define OFF_PV1    1461504              // [16][5][7][60] per-qt partial max
#define OFF_ASC    1495104              // att logit [16] (atomic accum)
#define OFF_LATT   1495120              // [64][16]
#define OFF_ABF    1496144              // u16[GM*GK]
#define OFF_WTMC   (OFF_ABF + GM*GK/2)  // u16[GN*GK]
#define OFF_WTMS   (OFF_WTMC + GN*GK/2) // float[600*768]

__device__ __forceinline__ u16 f2bf(float x) {
  union { float f; u32 u; } v; v.f = x;
  u32 r = v.u + 0x7FFFu + ((v.u >> 16) & 1u);
  return (u16)(r >> 16);
}

// ---------------------------------------------------------------------------
// MEGA-PREP (coalesced rewrite, R7): float4 gather, uint4 im2col, LDS-staged
// weight repacks.  4458 blocks total (was 18379 scalar blocks).
// blocks: [0,1313) gather f4 ; [1313,1361) mc zero f4 ; 1361 logit zero ;
//         [1362,3570) abuild uint4 ; [3570,4338) wtmc per-n ; [4338,4458)
//         wtms 64x64 tiled transpose.
#define PREP_GATHER_END  1313
#define PREP_MCZ_END     1361
#define PREP_LOGIT       1361
#define PREP_ABUILD_BEG  1362
#define PREP_ABUILD_END  3570
#define PREP_WTMC_END    4338
#define PREP_WTMS_END    4458

__global__ __launch_bounds__(256) void mega_prep_kernel(
    const float* __restrict__ embed,
    const int* __restrict__ mention_vec,
    const int* __restrict__ context_vec,
    const int* __restrict__ contexts_ids,
    const int* __restrict__ men2cands,
    const float* __restrict__ Wmc,
    const float* __restrict__ Wms,
    float* __restrict__ dst, float* __restrict__ mc,
    float* __restrict__ att_logit,
    u32* __restrict__ Abf, u32* __restrict__ WTmc, float* __restrict__ WTms) {
  __shared__ float psm[4160];   // wtmc: 1500 used; wtms: 64x65 tile
  int bid = blockIdx.x;
  int tid = threadIdx.x;
  if (bid < PREP_GATHER_END) {
    // gather embeddings as float4: 4480 rows x 75 f4
    int e4 = bid * 256 + tid;
    if (e4 < 4480 * 75) {
      int row = e4 / 75, c4 = e4 - row * 75;
      int tok;
      if (row < 256)       tok = mention_vec[row];
      else if (row < 3456) tok = contexts_ids[row - 256];
      else                 tok = men2cands[row - 3456];
      float4 v = *(const float4*)(embed + (size_t)tok * DDIM + c4 * 4);
      *(float4*)(dst + (size_t)row * DDIM + c4 * 4) = v;
    }
  } else if (bid < PREP_MCZ_END) {
    // mc zero: 49152 floats = 12288 f4, 48 blocks exact
    int e4 = (bid - PREP_GATHER_END) * 256 + tid;
    *(float4*)(mc + e4 * 4) = make_float4(0.f, 0.f, 0.f, 0.f);
  } else if (bid == PREP_LOGIT) {
    if (tid < NN) att_logit[tid] = 0.f;
  } else if (bid < PREP_ABUILD_END) {
    // im2col bf16: each thread emits one uint4 (8 bf16), 8 indep embed reads
    int idx4 = (bid - PREP_ABUILD_BEG) * 256 + tid;   // < 565248
    int r = idx4 / (GK / 8);
    int kq = idx4 - r * (GK / 8);
    int m = r / 46, t = r - m * 46;
    int kbase = kq * 8;
    u32 wlo[4];
#pragma unroll
    for (int q = 0; q < 4; q++) {
      u32 outw = 0;
#pragma unroll
      for (int j = 0; j < 2; j++) {
        int kj = kbase + q * 2 + j;
        u16 h = 0;
        if (kj < 1500) {
          int tap = kj / 300;
          int d = kj - tap * 300;
          int tok = context_vec[m * CTX_LL + t + tap];
          h = f2bf(embed[(size_t)tok * DDIM + d]);
        }
        outw |= (u32)h << (16 * j);
      }
      wlo[q] = outw;
    }
    ((uint4*)Abf)[idx4] = make_uint4(wlo[0], wlo[1], wlo[2], wlo[3]);
  } else if (bid < PREP_WTMC_END) {
    // wtmc: one block per n; stage Wmc row (1500 f) in LDS, write coalesced
    int n = bid - PREP_ABUILD_END;
    for (int i = tid; i < 1500; i += 256) psm[i] = Wmc[(size_t)n * 1500 + i];
    __syncthreads();
    for (int kp = tid; kp < GK / 2; kp += 256) {
      u32 outw = 0;
#pragma unroll
      for (int j = 0; j < 2; j++) {
        int kj = kp * 2 + j;
        u16 h = 0;
        if (kj < 1500) {
          int tap = kj / 300;
          int d = kj - tap * 300;
          h = f2bf(psm[d * 5 + tap]);
        }
        outw |= (u32)h << (16 * j);
      }
      WTmc[(size_t)n * (GK / 2) + kp] = outw;
    }
  } else {
    // wtms: 64x64 tiled transpose Wms[768][600] -> WTms[600][768]
    int tile = bid - PREP_WTMC_END;     // 0..119 = 10 ktiles x 12 ftiles
    int kt = tile / 12, ft = tile - kt * 12;
    int k0 = kt * 64, f0 = ft * 64;
    for (int idx = tid; idx < 64 * 64; idx += 256) {
      int i = idx >> 6, j = idx & 63;   // i = f-local, j = k-local
      if (k0 + j < 600)
        psm[j * 65 + i] = Wms[(size_t)(f0 + i) * 600 + (k0 + j)];
    }
    __syncthreads();
    for (int idx = tid; idx < 64 * 64; idx += 256) {
      int j = idx >> 6, i = idx & 63;   // j = k-local, i = f-local
      if (k0 + j < 600)
        WTms[(size_t)(k0 + j) * FNUM + (f0 + i)] = psm[j * 65 + i];
    }
  }
}

// ---------------------------------------------------------------------------
// bf16 MFMA GEMM body with fused relu+mean epilogue (atomicAdd into mc).
// As/Bs carved from the unified smem buffer (2304 floats each as u16[64][72]).
__device__ __forceinline__ void conv_gemm_body(
    const u16* __restrict__ A,    // [GM][GK] bf16
    const u16* __restrict__ B,    // [GN][GK] bf16 (n-major)
    const float* __restrict__ bias,
    float* __restrict__ mc, int g, float* __restrict__ smem) {
  int bn = g % (GN / 64), bm = g / (GN / 64);
  u16* As = (u16*)smem;            // [64][72]
  u16* Bs = (u16*)(smem + 2304);   // [64][72]
  int tid = threadIdx.x;
  int w = tid >> 6, lane = tid & 63;
  int wr = w >> 1, wc = w & 1;
  int lg = lane >> 4, lm = lane & 15;
  f32x4 acc[2][2];
#pragma unroll
  for (int i = 0; i < 2; i++)
#pragma unroll
    for (int j = 0; j < 2; j++) acc[i][j] = (f32x4)0.f;
  int c0row = tid >> 3, ck = (tid & 7) * 8;
  const u16* Ag = A + (size_t)(bm * 64) * GK;
  const u16* Bg = B + (size_t)(bn * 64) * GK;
  for (int kt = 0; kt < GK / 64; kt++) {
    int k0 = kt * 64;
    uint4 av0 = *(const uint4*)(Ag + (size_t)c0row * GK + k0 + ck);
    uint4 av1 = *(const uint4*)(Ag + (size_t)(c0row + 32) * GK + k0 + ck);
    uint4 bv0 = *(const uint4*)(Bg + (size_t)c0row * GK + k0 + ck);
    uint4 bv1 = *(const uint4*)(Bg + (size_t)(c0row + 32) * GK + k0 + ck);
    __syncthreads();
    *(uint4*)&As[c0row * 72 + ck] = av0;
    *(uint4*)&As[(c0row + 32) * 72 + ck] = av1;
    *(uint4*)&Bs[c0row * 72 + ck] = bv0;
    *(uint4*)&Bs[(c0row + 32) * 72 + ck] = bv1;
    __syncthreads();
#pragma unroll
    for (int kk = 0; kk < 2; kk++) {
      short8 af0 = *(const short8*)&As[(wr * 32 + lm) * 72 + kk * 32 + lg * 8];
      short8 af1 = *(const short8*)&As[(wr * 32 + 16 + lm) * 72 + kk * 32 + lg * 8];
      short8 bf0 = *(const short8*)&Bs[(wc * 32 + lm) * 72 + kk * 32 + lg * 8];
      short8 bf1 = *(const short8*)&Bs[(wc * 32 + 16 + lm) * 72 + kk * 32 + lg * 8];
      acc[0][0] = __builtin_amdgcn_mfma_f32_16x16x32_bf16(af0, bf0, acc[0][0], 0, 0, 0);
      acc[0][1] = __builtin_amdgcn_mfma_f32_16x16x32_bf16(af0, bf1, acc[0][1], 0, 0, 0);
      acc[1][0] = __builtin_amdgcn_mfma_f32_16x16x32_bf16(af1, bf0, acc[1][0], 0, 0, 0);
      acc[1][1] = __builtin_amdgcn_mfma_f32_16x16x32_bf16(af1, bf1, acc[1][1], 0, 0, 0);
    }
  }
#pragma unroll
  for (int mf = 0; mf < 2; mf++)
#pragma unroll
    for (int nf = 0; nf < 2; nf++) {
      int col = bn * 64 + wc * 32 + nf * 16 + lm;
      float bb = bias[col];
      int base = bm * 64 + wr * 32 + mf * 16 + lg * 4;
      int mcur = base / 46;
      float s = 0.f;
#pragma unroll
      for (int r = 0; r < 4; r++) {
        float v = fmaxf(acc[mf][nf][r] + bb, 0.f) * (1.0f / 46.0f);
        int mm = (base + r) / 46;
        if (mm != mcur) { atomicAdd(&mc[mcur * FNUM + col], s); s = 0.f; mcur = mm; }
        s += v;
      }
      atomicAdd(&mc[mcur * FNUM + col], s);
    }
}

// ---------------------------------------------------------------------------
// device bodies for the MEGA-MID kernel (Round-1 validated versions)
__device__ __forceinline__ void conv_ms_body(
    const float* __restrict__ msg, const float* __restrict__ WT,
    const float* __restrict__ B, float* __restrict__ ms, int b) {
  int m = b / 3, fi = b - m * 3;
  int f = fi * 256 + threadIdx.x;
  const float* x = msg + m * SURF_LL * DDIM;
  float a0 = 0.f, a1 = 0.f, a2 = 0.f;
  for (int d = 0; d < DDIM; d++) {
    float v0 = x[d], v1 = x[DDIM + d], v2 = x[2 * DDIM + d], v3 = x[3 * DDIM + d];
    float wA = WT[(size_t)(2 * d) * FNUM + f];
    float wB = WT[(size_t)(2 * d + 1) * FNUM + f];
    a0 += v0 * wA + v1 * wB;
    a1 += v1 * wA + v2 * wB;
    a2 += v2 * wA + v3 * wB;
  }
  float bb = B[f];
  float r = fmaxf(a0 + bb, 0.f) + fmaxf(a1 + bb, 0.f) + fmaxf(a2 + bb, 0.f);
  ms[m * FNUM + f] = r * (1.0f / 3.0f);
}

// Fused flash-attention block (Round-1 validated, 78.4us): QK^T + softmax +
// PV + q-maxpool.  K tile in LDS is also V.  P tile overlays dead Qs
// (wave-private rows).  smem: Ks 12400 + Qs/Pl 3200 + red 256 = 15856.
template <int DIR>
__device__ __forceinline__ void scores_pv_body(
    const float* __restrict__ embed, const int* __restrict__ doc_vec,
    const int* __restrict__ body_vec, float* __restrict__ pvp, int b,
    float* __restrict__ smem) {
  constexpr int Lq = DIR ? 200 : 100;
  constexpr int Lk = DIR ? 100 : 200;
  constexpr int KPL = DIR ? 2 : 4;
  constexpr int NQT = DIR ? 7 : 4;
  constexpr int NHALF = DIR ? 1 : 2;
  int qt = b / 80;
  int rem = b - qt * 80;
  int n = rem / 5, h = rem - n * 5;
  const int* qids = DIR ? body_vec + n * BODY_LL : doc_vec;
  const int* kids = DIR ? doc_vec : body_vec + n * BODY_LL;
  float* Ks = smem;              // [Lk][62]
  float* Qs = smem + 12400;      // [32][64]   (scores phase)
  float* Pl = smem + 12400;      // [32][100]  (PV phase, overlays Qs)
  float* red = smem + 15600;     // [4][64]
  for (int idx = threadIdx.x; idx < Lk * 15; idx += 256) {
    int r = idx / 15, c = idx - r * 15;
    float4 v = *(const float4*)(embed + (size_t)kids[r] * DDIM + h * HDIM + c * 4);
    float* dp = Ks + r * 62 + c * 4;
    dp[0] = v.x; dp[1] = v.y; dp[2] = v.z; dp[3] = v.w;
  }
  for (int idx = threadIdx.x; idx < 32 * 15; idx += 256) {
    int r = idx / 15, c = idx - r * 15;
    int q = qt * 32 + r; if (q >= Lq) q = Lq - 1;
    float4 v = *(const float4*)(embed + (size_t)qids[q] * DDIM + h * HDIM + c * 4);
    float* dp = Qs + r * 64 + c * 4;
    dp[0] = v.x; dp[1] = v.y; dp[2] = v.z; dp[3] = v.w;
  }
  __syncthreads();
  int w = threadIdx.x >> 6, lane = threadIdx.x & 63;
  int kcl[KPL];
#pragma unroll
  for (int j = 0; j < KPL; j++) {
    int kk = lane + 64 * j; kcl[j] = (kk < Lk) ? kk : (Lk - 1);
  }
  float acc[8][KPL];
#pragma unroll
  for (int i = 0; i < 8; i++)
#pragma unroll
    for (int j = 0; j < KPL; j++) acc[i][j] = 0.f;
  for (int d = 0; d < HDIM; d += 4) {
    float2 kva[KPL], kvb[KPL];
#pragma unroll
    for (int j = 0; j < KPL; j++) {
      kva[j] = *(const float2*)&Ks[kcl[j] * 62 + d];
      kvb[j] = *(const float2*)&Ks[kcl[j] * 62 + d + 2];
    }
#pragma unroll
    for (int i = 0; i < 8; i++) {
      float4 qv = *(const float4*)&Qs[(w * 8 + i) * 64 + d];
#pragma unroll
      for (int j = 0; j < KPL; j++)
        acc[i][j] += qv.x * kva[j].x + qv.y * kva[j].y +
                     qv.z * kvb[j].x + qv.w * kvb[j].y;
    }
  }
  const float scale = 0.12909944487358056f;  // 1/sqrt(60)
#pragma unroll
  for (int i = 0; i < 8; i++) {
    float mx = -1e30f;
#pragma unroll
    for (int j = 0; j < KPL; j++)
      if (lane + 64 * j < Lk) mx = fmaxf(mx, acc[i][j]);
#pragma unroll
    for (int o = 32; o >= 1; o >>= 1) mx = fmaxf(mx, __shfl_xor(mx, o));
    float mxs = mx * scale;
    float p[KPL];
    float s = 0.f;
#pragma unroll
    for (int j = 0; j < KPL; j++) {
      p[j] = (lane + 64 * j < Lk) ? __expf(acc[i][j] * scale - mxs) : 0.f;
      s += p[j];
    }
#pragma unroll
    for (int o = 32; o >= 1; o >>= 1) s += __shfl_xor(s, o);
    float inv = 1.0f / s;
#pragma unroll
    for (int j = 0; j < KPL; j++) acc[i][j] = p[j] * inv;  // normalized P in regs
  }
  // all waves done reading Qs before P overlays it
  __syncthreads();
  float o[8];
#pragma unroll
  for (int i = 0; i < 8; i++) o[i] = 0.f;
  int dl = (lane < HDIM) ? lane : (HDIM - 1);
#pragma unroll
  for (int half = 0; half < NHALF; half++) {
    int kbase = half * 100;
    // store this half's P entries (rows 8w..8w+7 are wave-private)
#pragma unroll
    for (int j = 0; j < KPL; j++) {
      int kk = lane + 64 * j;
      int rel = kk - kbase;
      if (rel >= 0 && rel < 100 && kk < Lk) {
#pragma unroll
        for (int i = 0; i < 8; i++)
          Pl[(w * 8 + i) * 100 + rel] = acc[i][j];
      }
    }
    // PV over this half's 100 k values (lane = output dim d)
    for (int k4 = 0; k4 < 25; k4++) {
      int k = kbase + k4 * 4;
      float kv0 = Ks[(k + 0) * 62 + dl];
      float kv1 = Ks[(k + 1) * 62 + dl];
      float kv2 = Ks[(k + 2) * 62 + dl];
      float kv3 = Ks[(k + 3) * 62 + dl];
#pragma unroll
      for (int i = 0; i < 8; i++) {
        float4 pq = *(const float4*)&Pl[(w * 8 + i) * 100 + k4 * 4];
        o[i] += pq.x * kv0 + pq.y * kv1 + pq.z * kv2 + pq.w * kv3;
      }
    }
  }
  // max over this wave's valid q rows
  float omax = -1e30f;
#pragma unroll
  for (int i = 0; i < 8; i++) {
    int q = qt * 32 + w * 8 + i;
    if (q < Lq) omax = fmaxf(omax, o[i]);
  }
  red[w * 64 + lane] = omax;
  __syncthreads();
  if (threadIdx.x < 64 && lane < HDIM) {
    float m4 = fmaxf(fmaxf(red[0 * 64 + lane], red[1 * 64 + lane]),
                     fmaxf(red[2 * 64 + lane], red[3 * 64 + lane]));
    pvp[((size_t)(n * NHEADS + h) * NQT + qt) * HDIM + lane] = m4;
  }
}

// tok + ctxv fused (Round-1 validated), one block per m.
__device__ __forceinline__ void tokctxv_body(
    const float* __restrict__ candg, const float* __restrict__ ctx2g,
    float* __restrict__ local_att, int m, float* __restrict__ smem) {
  float* cand  = smem;          // [16][300]
  float* ctx   = smem + 4800;   // [16][300]
  float* tokb  = smem + 9600;   // [16][17]
  float* tkmx  = smem + 9872;   // [64] (50 used)
  float* pp    = smem + 9936;   // [64]
  float* sctxv = smem + 10000;  // [300]
  int tid = threadIdx.x;
  for (int i = tid; i < NN * DDIM; i += 256)
    cand[i] = candg[(size_t)m * NN * DDIM + i];
  int nI = tid >> 4, tt = tid & 15;
  for (int tile = 0; tile < 4; tile++) {
    int cbase = tile * 16;
    __syncthreads();
    for (int i = tid; i < 16 * DDIM; i += 256) {
      int rr = i / DDIM, cc = i - rr * DDIM;
      int t = cbase + rr;
      ctx[rr * DDIM + cc] = (t < CTX_LL) ? ctx2g[(size_t)(m * CTX_LL + t) * DDIM + cc] : 0.f;
    }
    __syncthreads();
    const float4* ca = (const float4*)(cand + nI * DDIM);
    const float4* cb = (const float4*)(ctx + tt * DDIM);
    float dsum = 0.f;
#pragma unroll
    for (int c = 0; c < 75; c++) {
      float4 a = ca[c], b = cb[c];
      dsum += a.x * b.x + a.y * b.y + a.z * b.z + a.w * b.w;
    }
    tokb[nI * 17 + tt] = dsum;
    __syncthreads();
    if (tid < 16) {
      float mx = -1e30f;
      for (int nn = 0; nn < NN; nn++) mx = fmaxf(mx, tokb[nn * 17 + tid]);
      int t = cbase + tid;
      if (t < CTX_LL) tkmx[t] = mx;
    }
  }
  __syncthreads();
  if (tid < 64) {
    float v = (tid < CTX_LL) ? tkmx[tid] : -1e30f;
    float mx = v;
#pragma unroll
    for (int o = 32; o >= 1; o >>= 1) mx = fmaxf(mx, __shfl_xor(mx, o));
    float e = (tid < CTX_LL) ? expf(v - mx) : 0.f;
    float s = e;
#pragma unroll
    for (int o = 32; o >= 1; o >>= 1) s += __shfl_xor(s, o);
    pp[tid] = e / s;
  }
  __syncthreads();
  for (int d = tid; d < DDIM; d += 256) {
    float acc = 0.f;
    for (int t = 0; t < CTX_LL; t++)
      acc += pp[t] * ctx2g[(size_t)(m * CTX_LL + t) * DDIM + d];
    sctxv[d] = acc;
  }
  __syncthreads();
  int j = tid & 15;
  float dd = 0.f;
  for (int i = j; i < DDIM; i += 16) dd += cand[nI * DDIM + i] * sctxv[i];
#pragma unroll
  for (int o = 8; o >= 1; o >>= 1) dd += __shfl_xor(dd, o);
  if (j == 0) local_att[m * NN + nI] = dd;
}

// MEGA-MID+GEMM: [0,192) conv_ms ; [192,512) attn dir0 ; [512,1072) attn
// dir1 ; [1072,1136) tok+ctxv ; [1136,1688) conv_gemm.  Unified smem 15856
// floats (63.4 KB, 2 blocks/CU).  GEMM blocks last: their MFMA work
// co-schedules on the idle matrix pipe while attn waves stall on
// VALU/LDS (m114: separate pipes overlap fully).
__global__ __launch_bounds__(256) void mega_mid_kernel(
    const float* __restrict__ embed,
    const int* __restrict__ doc_vec,
    const int* __restrict__ body_vec,
    const float* __restrict__ msg,
    const float* __restrict__ WTms,
    const float* __restrict__ Bms,
    const float* __restrict__ candg,
    const float* __restrict__ ctx2g,
    const u16* __restrict__ Abf,
    const u16* __restrict__ WTmc,
    const float* __restrict__ Bmc,
    float* __restrict__ ms,
    float* __restrict__ mc,
    float* __restrict__ pv0,
    float* __restrict__ pv1,
    float* __restrict__ local_att) {
  __shared__ float smem[15856];
  int bid = blockIdx.x;
  if (bid < 192) {
    conv_ms_body(msg, WTms, Bms, ms, bid);
  } else if (bid < 512) {
    scores_pv_body<0>(embed, doc_vec, body_vec, pv0, bid - 192, smem);
  } else if (bid < 1072) {
    scores_pv_body<1>(embed, doc_vec, body_vec, pv1, bid - 512, smem);
  } else if (bid < 1136) {
    tokctxv_body(candg, ctx2g, local_att, bid - 1072, smem);
  } else {
    conv_gemm_body(Abf, WTmc, Bmc, mc, bid - 1136, smem);
  }
}

// ---------------------------------------------------------------------------
// MLP: 80 blocks = 16 n x 5 j-chunks of 60.  Each block: build comb[600]
// (max over qt partials), k-split across 4 waves, LDS-reduce, relu, dot w2,
// atomicAdd pre-sigmoid logit.  Sigmoid applied in final_kernel.
__global__ __launch_bounds__(256) void mlp_kernel(
    const float* __restrict__ pv0, const float* __restrict__ pv1,
    const float* __restrict__ w1, const float* __restrict__ b1,
    const float* __restrict__ w2,
    float* __restrict__ att_logit) {
  int bid = blockIdx.x;
  int n = bid / 5, jc = bid - n * 5;
  int tid = threadIdx.x;
  __shared__ float comb[600];
  __shared__ float partial[4][64];
  for (int idx = tid; idx < 600; idx += 256) {
    int side = idx >= 300;
    int pos = idx - side * 300;
    int h = pos / 60, d = pos - h * 60;
    float mx = -1e30f;
    if (!side) {
#pragma unroll
      for (int pt = 0; pt < 4; pt++)
        mx = fmaxf(mx, pv0[(size_t)((n * NHEADS + h) * 4 + pt) * HDIM + d]);
    } else {
#pragma unroll
      for (int pt = 0; pt < 7; pt++)
        mx = fmaxf(mx, pv1[(size_t)((n * NHEADS + h) * 7 + pt) * HDIM + d]);
    }
    comb[idx] = mx;
  }
  __syncthreads();
  int w = tid >> 6, lane = tid & 63;
  int jl = (lane < 60) ? lane : 59;
  int jg = jc * 60 + jl;
  float acc = 0.f;
  for (int k = w; k < 600; k += 4)
    acc += comb[k] * w1[(size_t)k * 300 + jg];
  partial[w][lane] = acc;
  __syncthreads();
  if (tid < 64) {
    float hv = partial[0][lane] + partial[1][lane] +
               partial[2][lane] + partial[3][lane];
    float hj = fmaxf(hv + b1[jg], 0.f) * w2[jg];
    if (lane >= 60) hj = 0.f;
#pragma unroll
    for (int o = 32; o >= 1; o >>= 1) hj += __shfl_xor(hj, o);
    if (lane == 0) atomicAdd(&att_logit[n], hj);
  }
}

// ---------------------------------------------------------------------------
__global__ __launch_bounds__(256) void final_kernel(
    const float* __restrict__ ms,
    const float* __restrict__ mc,
    const float* __restrict__ title,
    const float* __restrict__ bert,
    const float* __restrict__ att_logit,
    const float* __restrict__ b2,
    const float* __restrict__ m2c_prior,
    const float* __restrict__ hand,
    const float* __restrict__ local_att,
    const float* __restrict__ w7,
    const float* __restrict__ b7,
    float* __restrict__ out) {
  int m = blockIdx.x, tid = threadIdx.x;
  __shared__ float sms[FNUM], smc[FNUM], smd[FNUM];
  __shared__ float snorm[3], sscore[16], wred[3][4];
  for (int i = tid; i < FNUM; i += 256) {
    sms[i] = ms[m * FNUM + i];
    smc[i] = mc[m * FNUM + i];
    smd[i] = bert[i];
  }
  __syncthreads();
  float p1 = 0.f, p2 = 0.f, p3 = 0.f;
  for (int i = tid; i < FNUM; i += 256) {
    float a = sms[i], b = smc[i], c = smd[i];
    p1 += a * a; p2 += b * b; p3 += c * c;
  }
#pragma unroll
  for (int o = 32; o >= 1; o >>= 1) {
    p1 += __shfl_xor(p1, o); p2 += __shfl_xor(p2, o); p3 += __shfl_xor(p3, o);
  }
  int wid = tid >> 6, lane = tid & 63;
  if (lane == 0) { wred[0][wid] = p1; wred[1][wid] = p2; wred[2][wid] = p3; }
  __syncthreads();
  if (tid == 0) {
    snorm[0] = fmaxf(sqrtf(wred[0][0] + wred[0][1] + wred[0][2] + wred[0][3]), 1e-6f);
    snorm[1] = fmaxf(sqrtf(wred[1][0] + wred[1][1] + wred[1][2] + wred[1][3]), 1e-6f);
    snorm[2] = fmaxf(sqrtf(wred[2][0] + wred[2][1] + wred[2][2] + wred[2][3]), 1e-6f);
  }
  __syncthreads();
  int nI = tid >> 4, j = tid & 15;
  float d1 = 0.f, d2 = 0.f, d3 = 0.f, d4 = 0.f;
  for (int i = j; i < FNUM; i += 16) {
    float t = title[nI * FNUM + i];
    d1 += sms[i] * t; d2 += smc[i] * t; d3 += smd[i] * t; d4 += t * t;
  }
#pragma unroll
  for (int o = 8; o >= 1; o >>= 1) {
    d1 += __shfl_xor(d1, o); d2 += __shfl_xor(d2, o);
    d3 += __shfl_xor(d3, o); d4 += __shfl_xor(d4, o);
  }
  if (j == 0) {
    float nt = fmaxf(sqrtf(d4), 1e-6f);
    float cos_st = d1 / (snorm[0] * nt);
    float cos_ct = d2 / (snorm[1] * nt);
    float cos_dt = d3 / (snorm[2] * nt);
    float asc = 1.0f / (1.0f + expf(-(att_logit[nI] + b2[0])));
    float score = hand[nI] * w7[0] + m2c_prior[nI] * w7[1] +
                  local_att[m * NN + nI] * w7[2] + asc * w7[3] +
                  cos_st * w7[4] + cos_dt * w7[5] + cos_ct * w7[6] + b7[0];
    sscore[nI] = score;
  }
  __syncthreads();
  if (tid < 16) {
    float x = sscore[tid];
    float s = x;
#pragma unroll
    for (int o = 8; o >= 1; o >>= 1) s += __shfl_xor(s, o);
    float mu = s * (1.0f / 16.0f);
    float dv = (x - mu) * (x - mu);
    float vs = dv;
#pragma unroll
    for (int o = 8; o >= 1; o >>= 1) vs += __shfl_xor(vs, o);
    float sd = sqrtf(vs * (1.0f / 15.0f));
    float z = (x - mu) / sd;
    float zm = z;
#pragma unroll
    for (int o = 8; o >= 1; o >>= 1) zm = fmaxf(zm, __shfl_xor(zm, o));
    float e = expf(z - zm);
    float es = e;
#pragma unroll
    for (int o = 8; o >= 1; o >>= 1) es += __shfl_xor(es, o);
    float sm = e / es;
    float zmin = z;
#pragma unroll
    for (int o = 8; o >= 1; o >>= 1) zmin = fminf(zmin, __shfl_xor(zmin, o));
    float u0 = (z + 1.0f - zmin) / (zm - zmin);
    float us = u0;
#pragma unroll
    for (int o = 8; o >= 1; o >>= 1) us += __shfl_xor(us, o);
    float u = u0 / us;
    out[m * NN + tid] = z;
    out[MM * NN + m * NN + tid] = sm;
    out[2 * MM * NN + m * NN + tid] = u;
  }
}

// ---------------------------------------------------------------------------
extern "C" void kernel_launch(void* const* d_in, const int* in_sizes, int n_in,
                              void* d_out, int out_size, void* d_ws, size_t ws_size,
                              hipStream_t stream) {
  const int*   mention_vec   = (const int*)d_in[3];
  const int*   context_vec   = (const int*)d_in[4];
  const int*   doc_vec       = (const int*)d_in[5];
  const float* title_vec     = (const float*)d_in[6];
  const int*   body_vec      = (const int*)d_in[7];
  const float* m2c_prior     = (const float*)d_in[9];
  const int*   men2cands     = (const int*)d_in[10];
  const int*   contexts_ids  = (const int*)d_in[11];
  const float* hand_features = (const float*)d_in[12];
  const float* bert_doc_vec  = (const float*)d_in[13];
  const float* embed_table   = (const float*)d_in[14];
  const float* conv_ms_w     = (const float*)d_in[15];
  const float* conv_ms_b     = (const float*)d_in[16];
  const float* conv_mc_w     = (const float*)d_in[17];
  const float* conv_mc_b     = (const float*)d_in[18];
  const float* layer_local_w = (const float*)d_in[19];
  const float* layer_local_b = (const float*)d_in[20];
  const float* att_w1        = (const float*)d_in[21];
  const float* att_b1        = (const float*)d_in[22];
  const float* att_w2        = (const float*)d_in[23];
  const float* att_b2        = (const float*)d_in[24];

  float* ws     = (float*)d_ws;
  float* msg    = ws + OFF_MSG;
  float* ctx2g  = ws + OFF_CTX2G;
  float* candg  = ws + OFF_CANDG;
  float* ms     = ws + OFF_MS;
  float* mc     = ws + OFF_MC;
  float* pv0    = ws + OFF_PV0;
  float* pv1    = ws + OFF_PV1;
  float* att_lg = ws + OFF_ASC;
  float* latt   = ws + OFF_LATT;
  u16*   Abf    = (u16*)(ws + OFF_ABF);
  u16*   WTmc   = (u16*)(ws + OFF_WTMC);
  float* WTms   = ws + OFF_WTMS;
  float* out    = (float*)d_out;

  mega_prep_kernel<<<dim3(PREP_WTMS_END), dim3(256), 0, stream>>>(
      embed_table, mention_vec, context_vec, contexts_ids, men2cands,
      conv_mc_w, conv_ms_w, ws, mc, att_lg, (u32*)Abf, (u32*)WTmc, WTms);
  mega_mid_kernel<<<dim3(1688), dim3(256), 0, stream>>>(
      embed_table, doc_vec, body_vec, msg, WTms, conv_ms_b, candg, ctx2g,
      Abf, WTmc, conv_mc_b, ms, mc, pv0, pv1, latt);
  mlp_kernel<<<dim3(80), dim3(256), 0, stream>>>(
      pv0, pv1, att_w1, att_b1, att_w2, att_lg);
  final_kernel<<<dim3(MM), dim3(256), 0, stream>>>(
      ms, mc, title_vec, bert_doc_vec, att_lg, att_b2, m2c_prior,
      hand_features, latt, layer_local_w, layer_local_b, out);
}